// Round 12
// baseline (575.666 us; speedup 1.0000x reference)
//
#include <hip/hip_runtime.h>
#include <hip/hip_bf16.h>
#include <cstdint>
#include <cstddef>

#define PD 11
#define PP 121
#define NB 8

typedef _Float16 f16x8 __attribute__((ext_vector_type(8)));
typedef float    f32x4 __attribute__((ext_vector_type(4)));

#define GLOAD16(SRC, DST) __builtin_amdgcn_global_load_lds( \
    (const __attribute__((address_space(1))) void*)(SRC),   \
    (__attribute__((address_space(3))) void*)(DST), 16, 0, 0)

struct TinyArgs {
    const float* x[3]; const float* xp[3]; const float* h[3];
    const float* c[3]; const float* w[3]; const float* bi[3];
    float* oh[3]; float* oc[3];
};

// ---------------------------------------------------------------------------
__global__ void init_kernel(unsigned* __restrict__ slots, float* __restrict__ zg) {
    int t = threadIdx.x;
    if (t < 8) slots[t] = 0x007FFFFFu;  // enc(-inf)
    for (int i = t; i < 1024; i += 256) zg[i] = 0.f;
}

__device__ __forceinline__ float decode_max(const unsigned* slot) {
    unsigned mu = *slot;
    return (mu & 0x80000000u) ? __uint_as_float(mu ^ 0x80000000u) : __uint_as_float(~mu);
}

// ---------------------------------------------------------------------------
// fused fp32 NCHW -> fp16 NHWC transpose for x AND xp (blockIdx.z selects).
template<int C, int H, int TPX>
__global__ __launch_bounds__(256) void tpose_kernel(
    const float* __restrict__ xin, const float* __restrict__ xpin,
    _Float16* __restrict__ xT, _Float16* __restrict__ xpT)
{
    constexpr int W = H;
    const float* in  = blockIdx.z ? xpin : xin;
    _Float16*   out  = blockIdx.z ? xpT  : xT;
    const int by = blockIdx.y;
    const int b  = by / H, y = by % H;
    constexpr int NXT = W / TPX;
    const int x0 = (blockIdx.x % NXT) * TPX;
    const int cc = (blockIdx.x / NXT) * 64;
    __shared__ float s[64][36];

    constexpr int NF4 = 64 * TPX / 4;
    for (int f = threadIdx.x; f < NF4; f += 256) {
        int r  = f / (TPX / 4);
        int xq = f % (TPX / 4);
        int col = (xq * 4) ^ (((r >> 3) & 7) * 4);
        *(float4*)&s[r][col] =
            *(const float4*)&in[((size_t)(b * C + cc + r) * H + y) * W + x0 + xq * 4];
    }
    __syncthreads();
    constexpr int NWT = TPX * 8;
    for (int t = threadIdx.x; t < NWT; t += 256) {
        int pix = t >> 3, ck = t & 7;
        union { _Float16 h[8]; f16x8 v; } d;
#pragma unroll
        for (int j = 0; j < 8; ++j)
            d.h[j] = (_Float16)s[ck * 8 + j][pix ^ (ck * 4)];
        *(f16x8*)&out[((size_t)(b * H + y) * W + x0 + pix) * C + cc + ck * 8] = d.v;
    }
}

// ---------------------------------------------------------------------------
// MFMA correlation, double-buffered gload_lds staging. RAW leaky'd corr ->
// inT channels [0,128) + block max -> atomicMax.
template<int C, int H, int TSY, int TSX>
__global__ __launch_bounds__(512, 2) void corr_mfma_kernel(
    const _Float16* __restrict__ xT, const _Float16* __restrict__ xpT,
    const _Float16* __restrict__ zg,
    _Float16* __restrict__ inT, unsigned* __restrict__ slot)
{
    constexpr int W  = H;
    constexpr int HY = TSY + 10, HX = TSX + 10;
    constexpr int MZ = HY * HX;
    constexpr int MT = (MZ + 15) / 16;
    constexpr int MTP = MT * 16;
    constexpr int MFRAG = (MT + 7) / 8;
    constexpr int NPX = TSY * TSX;
    constexpr int NT  = NPX / 16;
    constexpr int KC  = C / 32;
    constexpr int ABYTES = MTP * 64;
    constexpr int BUF    = ABYTES + NPX * 64;
    constexpr int NLOAD  = BUF / 1024;
    constexpr int ST2    = NPX + 8;
    constexpr int ST_B   = MTP * ST2 * 2;
    constexpr int LDS_B  = (2 * BUF > ST_B) ? 2 * BUF : ST_B;
    __shared__ char smem[LDS_B];
    __shared__ float sred[8];

    const int tid  = threadIdx.x;
    const int b    = blockIdx.y;
    constexpr int TXT = W / TSX;
    const int y0 = (blockIdx.x / TXT) * TSY;
    const int x0 = (blockIdx.x % TXT) * TSX;
    const int w = tid >> 6, lane = tid & 63;
    const int lcol = lane & 15, lkg = lane >> 4;

    auto STAGE = [&](int bufsel, int kc) {
        char* dstb = smem + bufsel * BUF;
        int c = lane & 3;
        for (int it = w; it < NLOAD; it += 8) {
            const void* src;
            if (it < MTP / 16) {
                int z = it * 16 + (lane >> 2);
                int zy = y0 + z / HX - 5, zx = x0 + z % HX - 5;
                if (z < MZ && zy >= 0 && zy < H && zx >= 0 && zx < W)
                    src = xpT + ((size_t)(b * H + zy) * W + zx) * C + kc * 32 + ((c ^ (z >> 2)) & 3) * 8;
                else
                    src = zg + lane * 8;
            } else {
                int p = (it - MTP / 16) * 16 + (lane >> 2);
                int gy = y0 + p / TSX, gx = x0 + p % TSX;
                src = xT + ((size_t)(b * H + gy) * W + gx) * C + kc * 32 + ((c ^ (p >> 2)) & 3) * 8;
            }
            GLOAD16(src, dstb + it * 1024);
        }
    };

    f32x4 acc[MFRAG][NT];
#pragma unroll
    for (int i = 0; i < MFRAG; ++i)
#pragma unroll
        for (int nt = 0; nt < NT; ++nt)
            acc[i][nt] = (f32x4){0.f, 0.f, 0.f, 0.f};

    STAGE(0, 0);
    __syncthreads();
#pragma unroll 1
    for (int kc = 0; kc < KC; ++kc) {
        if (kc + 1 < KC) STAGE((kc + 1) & 1, kc + 1);
        const char* bb = smem + (kc & 1) * BUF;
        f16x8 bF[NT];
#pragma unroll
        for (int nt = 0; nt < NT; ++nt) {
            int p = nt * 16 + lcol;
            bF[nt] = *(const f16x8*)(bb + ABYTES + p * 64 + (((lkg ^ (p >> 2)) & 3) << 4));
        }
#pragma unroll
        for (int i = 0; i < MFRAG; ++i) {
            int mt = w + i * 8;
            if (mt < MT) {
                int z = mt * 16 + lcol;
                f16x8 aF = *(const f16x8*)(bb + z * 64 + (((lkg ^ (z >> 2)) & 3) << 4));
#pragma unroll
                for (int nt = 0; nt < NT; ++nt)
                    acc[i][nt] = __builtin_amdgcn_mfma_f32_16x16x32_f16(aF, bF[nt], acc[i][nt], 0, 0, 0);
            }
        }
        __syncthreads();
    }

    _Float16* sT = (_Float16*)smem;
#pragma unroll
    for (int i = 0; i < MFRAG; ++i) {
        int mt = w + i * 8;
        if (mt >= MT) continue;
        int z0 = mt * 16 + lkg * 4;
#pragma unroll
        for (int nt = 0; nt < NT; ++nt) {
            int p = nt * 16 + lcol;
#pragma unroll
            for (int r = 0; r < 4; ++r)
                sT[(z0 + r) * ST2 + p] = (_Float16)acc[i][nt][r];
        }
    }
    __syncthreads();

    float lmax = -3.4e38f;
    if (tid < NPX * 8) {
        int p  = tid >> 3;
        int qg = tid & 7;
        int py = p / TSX, px = p % TSX;
        size_t pix = (size_t)(b * H + y0 + py) * W + (x0 + px);
        unsigned* dst = (unsigned*)(inT + pix * 256) + qg * 8;
#pragma unroll
        for (int j2 = 0; j2 < 8; ++j2) {
            int q0 = qg * 16 + j2 * 2, q1 = q0 + 1;
            int qc0 = q0 < PP ? q0 : PP - 1;
            int qc1 = q1 < PP ? q1 : PP - 1;
            float v0 = (float)sT[((py + qc0 / PD) * HX + (px + qc0 % PD)) * ST2 + p];
            float v1 = (float)sT[((py + qc1 / PD) * HX + (px + qc1 % PD)) * ST2 + p];
            v0 = v0 > 0.f ? v0 : 0.01f * v0;
            v1 = v1 > 0.f ? v1 : 0.01f * v1;
            if (q0 < PP) lmax = fmaxf(lmax, v0);
            if (q1 < PP) lmax = fmaxf(lmax, v1);
            union { _Float16 h[2]; unsigned u; } pk;
            pk.h[0] = (_Float16)v0; pk.h[1] = (_Float16)v1;
            dst[j2] = pk.u;
        }
    }
    for (int off = 32; off; off >>= 1) lmax = fmaxf(lmax, __shfl_down(lmax, off));
    if (lane == 0) sred[w] = lmax;
    __syncthreads();
    if (tid == 0) {
        float m = sred[0];
        for (int i = 1; i < 8; ++i) m = fmaxf(m, sred[i]);
        unsigned eb = __float_as_uint(m);
        eb = (eb & 0x80000000u) ? ~eb : (eb | 0x80000000u);
        atomicMax(slot, eb);
    }
}

// ---------------------------------------------------------------------------
// coalesced weight pack body: block (mt, ks) stages 16 rows x 288 floats of W
// contiguously in LDS, emits 9 fragment blocks (u32-coalesced writes).
// corr columns (ic<121) prescaled by inv.
__device__ __forceinline__ void pack2_body(
    const float* __restrict__ Wsrc, _Float16* __restrict__ Apack,
    float inv, int mt, int ks, int tid, float* __restrict__ sW)
{
    const int icmax9 = (242 - ks * 32) * 9;
    for (int f = tid; f < 16 * 288; f += 256) {
        int r = f / 288, i = f - r * 288;
        int m = mt * 16 + r;
        float v = 0.f;
        if (m < 484 && i < icmax9) {
            int q = m >> 2, g = m & 3;
            v = Wsrc[((size_t)(g * PP + q) * 242 + ks * 32) * 9 + i];
        }
        sW[r * 292 + i] = v;
    }
    __syncthreads();
    const int o = tid * 2;
    const int l = o >> 3, e0 = o & 7;
    const int r = l & 15;
    const int klbase = (l >> 4) * 8;
    const int ic0 = ks * 32 + klbase + e0;
#pragma unroll 1
    for (int k9 = 0; k9 < 9; ++k9) {
        float v0 = sW[r * 292 + (klbase + e0) * 9 + k9];
        float v1 = sW[r * 292 + (klbase + e0 + 1) * 9 + k9];
        if (ic0 < PP)     v0 *= inv;
        if (ic0 + 1 < PP) v1 *= inv;
        union { _Float16 h[2]; unsigned u; } pk;
        pk.h[0] = (_Float16)v0; pk.h[1] = (_Float16)v1;
        *(unsigned*)((char*)Apack + (size_t)((k9 * 8 + ks) * 32 + mt) * 1024 + o * 2) = pk.u;
    }
}

// ---------------------------------------------------------------------------
// merged post-corr kernel for big levels: blocks [0,256) = pack, rest = h-fill.
template<int H>
__global__ __launch_bounds__(256) void post_kernel(
    _Float16* __restrict__ inT, const float* __restrict__ hpre,
    const float* __restrict__ Wsrc, _Float16* __restrict__ Apack,
    const unsigned* __restrict__ slot)
{
    __shared__ float sW[16 * 292];
    const int bx = blockIdx.x, tid = threadIdx.x;
    if (bx < 256) {
        float inv = 1.0f / decode_max(slot);
        pack2_body(Wsrc, Apack, inv, bx >> 3, bx & 7, tid, sW);
        return;
    }
    constexpr int HW = H * H;
    constexpr int NP = NB * HW;
    int idx = (bx - 256) * 256 + tid;
    if (idx >= NP * 17) return;
    int c = 15 + idx / NP;
    int pix = idx % NP;
    int b = pix / HW, p2 = pix % HW;
    _Float16* base = inT + (size_t)pix * 256 + c * 8;
    union { _Float16 h[8]; uint4 u; } d;
    if (c == 15) {
        d.u = *(const uint4*)base;
#pragma unroll
        for (int j = 1; j < 8; ++j)
            d.h[j] = (_Float16)hpre[((size_t)b * PP + (j - 1)) * HW + p2];
    } else if (c <= 29) {
#pragma unroll
        for (int j = 0; j < 8; ++j)
            d.h[j] = (_Float16)hpre[((size_t)b * PP + (c * 8 + j - 121)) * HW + p2];
    } else if (c == 30) {
        d.h[0] = (_Float16)hpre[((size_t)b * PP + 119) * HW + p2];
        d.h[1] = (_Float16)hpre[((size_t)b * PP + 120) * HW + p2];
#pragma unroll
        for (int j = 2; j < 8; ++j) d.h[j] = (_Float16)0.f;
    } else {
#pragma unroll
        for (int j = 0; j < 8; ++j) d.h[j] = (_Float16)0.f;
    }
    *(uint4*)base = d.u;
}

// ---------------------------------------------------------------------------
// tiny levels (H=8/4/2): batched corr + h-fill in one launch.
template<int H>
__device__ void corr_small_body(const float* __restrict__ x, const float* __restrict__ xp,
    _Float16* __restrict__ inT, unsigned* __restrict__ slot, int b)
{
    constexpr int PX  = H * H;
    constexpr int TOT = PX * PP;
    const int o = blockIdx.x * 256 + threadIdx.x;
    float v = -3.4e38f;
    if (o < TOT) {
        int p = o / PP;
        int q = o - p * PP;
        int y = p / H, xx = p % H;
        int sy = y + q / PD - 5, sx = xx + q % PD - 5;
        float acc = 0.f;
        if (sy >= 0 && sy < H && sx >= 0 && sx < H) {
            const float* xb  = x  + (size_t)b * 256 * PX + p;
            const float* xpb = xp + (size_t)b * 256 * PX + sy * H + sx;
#pragma unroll 8
            for (int c = 0; c < 256; ++c)
                acc = fmaf(xb[c * PX], xpb[c * PX], acc);
        }
        float lv = acc > 0.f ? acc : 0.01f * acc;
        inT[((size_t)b * PX + p) * 256 + q] = (_Float16)lv;
        v = lv;
    }
    for (int off = 32; off; off >>= 1) v = fmaxf(v, __shfl_down(v, off));
    __shared__ float sred[4];
    if ((threadIdx.x & 63) == 0) sred[threadIdx.x >> 6] = v;
    __syncthreads();
    if (threadIdx.x == 0) {
        float m = fmaxf(fmaxf(sred[0], sred[1]), fmaxf(sred[2], sred[3]));
        unsigned eb = __float_as_uint(m);
        eb = (eb & 0x80000000u) ? ~eb : (eb | 0x80000000u);
        atomicMax(slot, eb);
    }
}

template<int H>
__device__ void hfill_body(_Float16* __restrict__ inT, const float* __restrict__ hpre, int b)
{
    constexpr int HW = H * H;
    int idx = blockIdx.x * 256 + threadIdx.x;
    if (idx >= HW * 17) return;
    int c = 15 + idx / HW;
    int p2 = idx % HW;
    _Float16* base = inT + ((size_t)b * HW + p2) * 256 + c * 8;
    union { _Float16 h[8]; uint4 u; } d;
    if (c == 15) {
        d.u = *(const uint4*)base;
#pragma unroll
        for (int j = 1; j < 8; ++j)
            d.h[j] = (_Float16)hpre[((size_t)b * PP + (j - 1)) * HW + p2];
    } else if (c <= 29) {
#pragma unroll
        for (int j = 0; j < 8; ++j)
            d.h[j] = (_Float16)hpre[((size_t)b * PP + (c * 8 + j - 121)) * HW + p2];
    } else if (c == 30) {
        d.h[0] = (_Float16)hpre[((size_t)b * PP + 119) * HW + p2];
        d.h[1] = (_Float16)hpre[((size_t)b * PP + 120) * HW + p2];
#pragma unroll
        for (int j = 2; j < 8; ++j) d.h[j] = (_Float16)0.f;
    } else {
#pragma unroll
        for (int j = 0; j < 8; ++j) d.h[j] = (_Float16)0.f;
    }
    *(uint4*)base = d.u;
}

__global__ __launch_bounds__(256) void tiny_pre_kernel(
    TinyArgs ta, _Float16* __restrict__ inT, unsigned* __restrict__ slots)
{
    const int z = blockIdx.z, b = blockIdx.y;
    if      (z == 0) corr_small_body<8>(ta.x[0], ta.xp[0], inT,          slots + 3, b);
    else if (z == 1) corr_small_body<4>(ta.x[1], ta.xp[1], inT + 131072, slots + 4, b);
    else if (z == 2) corr_small_body<2>(ta.x[2], ta.xp[2], inT + 163840, slots + 5, b);
    else if (z == 3) hfill_body<8>(inT,          ta.h[0], b);
    else if (z == 4) hfill_body<4>(inT + 131072, ta.h[1], b);
    else             hfill_body<2>(inT + 163840, ta.h[2], b);
}

__global__ __launch_bounds__(256) void pack_tiny_kernel(
    TinyArgs ta, _Float16* __restrict__ a0, _Float16* __restrict__ a1,
    _Float16* __restrict__ a2, const unsigned* __restrict__ slots)
{
    __shared__ float sW[16 * 292];
    const int z = blockIdx.z;
    _Float16* Ap = (z == 0) ? a0 : (z == 1 ? a1 : a2);
    float inv = 1.0f / decode_max(slots + 3 + z);
    pack2_body(ta.w[z], Ap, inv, blockIdx.x >> 3, blockIdx.x & 7, threadIdx.x, sW);
}

// ---------------------------------------------------------------------------
// conv v3: TR x 16 tile, gload_lds staging, A AND B register double-buffers,
// setprio around MFMA clusters. TR=4, MSPLIT in {1,2,4}.
template<int H, int TR, int MSPLIT>
__global__ __launch_bounds__(512, 4) void conv_mfma3_kernel(
    const _Float16* __restrict__ inT, const float* __restrict__ cpre,
    const _Float16* __restrict__ Apack, const float* __restrict__ bias,
    const _Float16* __restrict__ zg,
    float* __restrict__ outh, float* __restrict__ outc)
{
    constexpr int W = H;
    constexpr int TC = 16, SR = TC + 2;
    constexpr int NPOS = (TR + 2) * SR;
    constexpr int MT_BLK = 32 / MSPLIT;
    constexpr int AF = 4 / MSPLIT;
    constexpr int TILES_X = W / TC;
    __shared__ _Float16 sIn[NPOS * 256];

    const int tid  = threadIdx.x;
    const int b    = blockIdx.y;
    const int mblk = blockIdx.z;
    const int tile = blockIdx.x;
    const int ty0  = (tile / TILES_X) * TR;
    const int tx0  = (tile % TILES_X) * TC;
    const int w = tid >> 6, lane = tid & 63;
    const int lcol = lane & 15, kg = lane >> 4;

    char* sB = (char*)sIn;
    for (int it = w; it < NPOS / 2; it += 8) {
        int r  = it * 2 + (lane >> 5);
        int c  = lane & 31;
        int iy = r / SR, ix = r % SR;
        int gy = ty0 + iy - 1, gx = tx0 + ix - 1;
        const void* src;
        if (gy >= 0 && gy < H && gx >= 0 && gx < W)
            src = inT + ((size_t)(b * H + gy) * W + gx) * 256 + (c ^ (ix & 7)) * 8;
        else
            src = zg + lane * 8;
        GLOAD16(src, sB + it * 1024);
    }
    __syncthreads();

    const int mtg0 = mblk * MT_BLK + w * AF;

    f32x4 acc[AF * TR];
#pragma unroll
    for (int a = 0; a < AF; ++a) {
        int q = (mtg0 + a) * 4 + kg;
        f32x4 bv;
#pragma unroll
        for (int r = 0; r < 4; ++r) bv[r] = (q < PP) ? bias[r * PP + q] : 0.f;
#pragma unroll
        for (int j = 0; j < TR; ++j) acc[a * TR + j] = bv;
    }

    const f16x8* apL = (const f16x8*)Apack + (size_t)mtg0 * 64 + lane;

    auto LOADA = [&](f16x8* af, int s) {
        const f16x8* ap = apL + (size_t)s * 2048;
#pragma unroll
        for (int a = 0; a < AF; ++a) af[a] = ap[a * 64];
    };
    auto LOADB = [&](f16x8* bf, int s) {
        int k9 = s >> 3, ks = s & 7;
        int ky = k9 / 3, kx = k9 - ky * 3;
        int ix = lcol + kx;
        int xsw = (ix & 7) << 4;
        int cb  = kg * 16 + ks * 64;
#pragma unroll
        for (int j = 0; j < TR; ++j)
            bf[j] = *(const f16x8*)(sB + ((((j + ky) * SR + ix) * 512 + cb) ^ xsw));
    };
    auto DOMFMA = [&](const f16x8* af, const f16x8* bf) {
        __builtin_amdgcn_s_setprio(1);
#pragma unroll
        for (int j = 0; j < TR; ++j)
#pragma unroll
            for (int a = 0; a < AF; ++a)
                acc[a * TR + j] = __builtin_amdgcn_mfma_f32_16x16x32_f16(af[a], bf[j], acc[a * TR + j], 0, 0, 0);
        __builtin_amdgcn_s_setprio(0);
    };

    f16x8 afA[AF], afB[AF], bfA[TR], bfB[TR];
    LOADA(afA, 0); LOADB(bfA, 0);
#pragma unroll 1
    for (int s2 = 0; s2 < 36; ++s2) {
        LOADA(afB, 2 * s2 + 1); LOADB(bfB, 2 * s2 + 1);
        DOMFMA(afA, bfA);
        if (s2 < 35) { LOADA(afA, 2 * s2 + 2); LOADB(bfA, 2 * s2 + 2); }
        DOMFMA(afB, bfB);
    }

#pragma unroll
    for (int a = 0; a < AF; ++a) {
        int q = (mtg0 + a) * 4 + kg;
        if (q >= PP) continue;
#pragma unroll
        for (int j = 0; j < TR; ++j) {
            int y = ty0 + j, x = tx0 + lcol;
            if (y >= H) continue;
            float ai = acc[a * TR + j][0];
            float af_ = acc[a * TR + j][1];
            float ao = acc[a * TR + j][2];
            float ag = acc[a * TR + j][3];
            float ig = 1.f / (1.f + expf(-ai));
            float fg = 1.f / (1.f + expf(-af_));
            float og = 1.f / (1.f + expf(-ao));
            float gg = tanhf(ag);
            size_t oidx = (((size_t)b * PP + q) * H + y) * W + x;
            float cp = cpre[oidx];
            float cn = fg * cp + ig * gg;
            outh[oidx] = og * tanhf(cn);
            outc[oidx] = cn;
        }
    }
}

// ---------------------------------------------------------------------------
// batched tiny conv: whole image per block, M-split over blockIdx.x, level
// over blockIdx.z (compile-time bodies).
template<int H>
__device__ void conv_tiny_body(const _Float16* __restrict__ inT,
    const float* __restrict__ cpre, const _Float16* __restrict__ Apack,
    const float* __restrict__ bias, float* __restrict__ outh,
    float* __restrict__ outc, int b, int mblk, char* __restrict__ sB)
{
    constexpr int NPX = H * H;
    constexpr int NT  = (NPX + 15) / 16;
    constexpr int SR  = H + 2;
    constexpr int NPOS = SR * SR;
    const int tid = threadIdx.x;

    constexpr int CHUNKS = NPOS * 32;
    for (int flat = tid; flat < CHUNKS; flat += 512) {
        int cg  = flat & 31;
        int pos = flat >> 5;
        int iy = pos / SR, ix = pos % SR;
        int gy = iy - 1, gx = ix - 1;
        f16x8 v = {0, 0, 0, 0, 0, 0, 0, 0};
        if (gy >= 0 && gy < H && gx >= 0 && gx < H)
            v = *(const f16x8*)(inT + ((size_t)(b * H + gy) * H + gx) * 256 + cg * 8);
        int dst = (pos * 512 + cg * 16) ^ ((ix & 7) << 4);
        *(f16x8*)(sB + dst) = v;
    }
    __syncthreads();

    const int w = tid >> 6, lane = tid & 63;
    const int lcol = lane & 15, kg = lane >> 4;
    const int mt = mblk * 8 + w;
    const int q  = mt * 4 + kg;

    f32x4 acc[NT];
    f32x4 bv;
#pragma unroll
    for (int r = 0; r < 4; ++r) bv[r] = (q < PP) ? bias[r * PP + q] : 0.f;
#pragma unroll
    for (int nt = 0; nt < NT; ++nt) acc[nt] = bv;

#pragma unroll 1
    for (int k9 = 0; k9 < 9; ++k9) {
        const int ky = k9 / 3, kx = k9 % 3;
        int basev[NT], xswv[NT];
#pragma unroll
        for (int nt = 0; nt < NT; ++nt) {
            int p = nt * 16 + lcol;
            int pc = (NPX < 16 && p >= NPX) ? 0 : p;
            int py = pc / H, px = pc % H;
            int iy = py + ky, ix = px + kx;
            basev[nt] = (iy * SR + ix) * 512 + kg * 16;
            xswv[nt]  = (ix & 7) << 4;
        }
        const f16x8* apb = (const f16x8*)Apack + ((size_t)(k9 * 8) * 32 + mt) * 64 + lane;
#pragma unroll 1
        for (int ks = 0; ks < 8; ++ks) {
            f16x8 bf[NT];
#pragma unroll
            for (int nt = 0; nt < NT; ++nt) {
                bf[nt] = *(const f16x8*)(sB + ((basev[nt] + ks * 64) ^ xswv[nt]));
                if (NPX < 16 && nt * 16 + lcol >= NPX) bf[nt] = (f16x8){};
            }
            f16x8 af = apb[(size_t)ks * 32 * 64];
#pragma unroll
            for (int nt = 0; nt < NT; ++nt)
                acc[nt] = __builtin_amdgcn_mfma_f32_16x16x32_f16(af, bf[nt], acc[nt], 0, 0, 0);
        }
    }

    if (q < PP) {
#pragma unroll
        for (int nt = 0; nt < NT; ++nt) {
            int p = nt * 16 + lcol;
            if (NPX < 16 && p >= NPX) continue;
            int py = p / H, px = p % H;
            float ai = acc[nt][0];
            float af_ = acc[nt][1];
            float ao = acc[nt][2];
            float ag = acc[nt][3];
            float ig = 1.f / (1.f + expf(-ai));
            float fg = 1.f / (1.f + expf(-af_));
            float og = 1.f / (1.f + expf(-ao));
            float gg = tanhf(ag);
            size_t oidx = (((size_t)b * PP + q) * H + py) * H + px;
            float cp = cpre[oidx];
            float cn = fg * cp + ig * gg;
            outh[oidx] = og * tanhf(cn);
            outc[oidx] = cn;
        }
    }
}

__global__ __launch_bounds__(512, 4) void conv_tiny_kernel(
    TinyArgs ta, const _Float16* __restrict__ inT,
    const _Float16* __restrict__ a0, const _Float16* __restrict__ a1,
    const _Float16* __restrict__ a2)
{
    __shared__ char sB[100 * 512];
    const int z = blockIdx.z, b = blockIdx.y, mblk = blockIdx.x;
    if      (z == 0) conv_tiny_body<8>(inT,          ta.c[0], a0, ta.bi[0], ta.oh[0], ta.oc[0], b, mblk, sB);
    else if (z == 1) conv_tiny_body<4>(inT + 131072, ta.c[1], a1, ta.bi[1], ta.oh[1], ta.oc[1], b, mblk, sB);
    else             conv_tiny_body<2>(inT + 163840, ta.c[2], a2, ta.bi[2], ta.oh[2], ta.oc[2], b, mblk, sB);
}

// ---------------------------------------------------------------------------
extern "C" void kernel_launch(void* const* d_in, const int* in_sizes, int n_in,
                              void* d_out, int out_size, void* d_ws, size_t ws_size,
                              hipStream_t stream) {
    (void)in_sizes; (void)n_in; (void)out_size; (void)ws_size;
    static const int HH[6] = {64, 32, 16, 8, 4, 2};

    unsigned* maxslots = (unsigned*)d_ws;
    _Float16* Apack = (_Float16*)((char*)d_ws + 256);
    _Float16* inT   = (_Float16*)((char*)d_ws + 2359808);
    _Float16* xT    = (_Float16*)((char*)d_ws + 19137024);
    _Float16* xpT   = (_Float16*)((char*)d_ws + 52691456);
    _Float16* zg    = (_Float16*)((char*)d_ws + 86245888);
    // tiny-level Apacks reuse the (dead-after-corr-L2) xT region
    _Float16* apT0 = (_Float16*)((char*)d_ws + 19137024);
    _Float16* apT1 = (_Float16*)((char*)d_ws + 19137024 + 2359296);
    _Float16* apT2 = (_Float16*)((char*)d_ws + 19137024 + 2 * 2359296);

    float* out = (float*)d_out;
    size_t obase[6];
    {
        size_t ob = 0;
        for (int L = 0; L < 6; ++L) { obase[L] = ob; ob += 2ull * NB * PP * HH[L] * HH[L]; }
    }

    init_kernel<<<1, 256, 0, stream>>>(maxslots, (float*)zg);

    // ---- big levels 0..2 ----
    for (int L = 0; L < 3; ++L) {
        const float* x    = (const float*)d_in[6 * L + 0];
        const float* xp   = (const float*)d_in[6 * L + 1];
        const float* h    = (const float*)d_in[6 * L + 2];
        const float* c    = (const float*)d_in[6 * L + 3];
        const float* Wsrc = (const float*)d_in[6 * L + 4];
        const float* bias = (const float*)d_in[6 * L + 5];
        int Hh = HH[L];
        int S = NB * PP * Hh * Hh;
        float* oh = out + obase[L];
        float* oc = out + obase[L] + S;

        switch (L) {
            case 0:
                tpose_kernel<512, 64, 32><<<dim3(16, NB * 64, 2), 256, 0, stream>>>(x, xp, xT, xpT);
                corr_mfma_kernel<512, 64, 8, 8><<<dim3(64, NB), 512, 0, stream>>>(xT, xpT, zg, inT, maxslots + 0);
                post_kernel<64><<<256 + (NB * 64 * 64 * 17 + 255) / 256, 256, 0, stream>>>(inT, h, Wsrc, Apack, maxslots + 0);
                conv_mfma3_kernel<64, 4, 1><<<dim3(64, 8, 1), 512, 0, stream>>>(inT, c, Apack, bias, zg, oh, oc);
                break;
            case 1:
                tpose_kernel<1024, 32, 32><<<dim3(16, NB * 32, 2), 256, 0, stream>>>(x, xp, xT, xpT);
                corr_mfma_kernel<1024, 32, 4, 8><<<dim3(32, NB), 512, 0, stream>>>(xT, xpT, zg, inT, maxslots + 1);
                post_kernel<32><<<256 + (NB * 32 * 32 * 17 + 255) / 256, 256, 0, stream>>>(inT, h, Wsrc, Apack, maxslots + 1);
                conv_mfma3_kernel<32, 4, 2><<<dim3(16, 8, 2), 512, 0, stream>>>(inT, c, Apack, bias, zg, oh, oc);
                break;
            case 2:
                tpose_kernel<512, 16, 16><<<dim3(8, NB * 16, 2), 256, 0, stream>>>(x, xp, xT, xpT);
                corr_mfma_kernel<512, 16, 4, 4><<<dim3(16, NB), 512, 0, stream>>>(xT, xpT, zg, inT, maxslots + 2);
                post_kernel<16><<<256 + (NB * 16 * 16 * 17 + 255) / 256, 256, 0, stream>>>(inT, h, Wsrc, Apack, maxslots + 2);
                conv_mfma3_kernel<16, 4, 4><<<dim3(4, 8, 4), 512, 0, stream>>>(inT, c, Apack, bias, zg, oh, oc);
                break;
        }
    }

    // ---- tiny levels 3..5, batched ----
    TinyArgs ta;
    for (int i = 0; i < 3; ++i) {
        int L = 3 + i;
        ta.x[i]  = (const float*)d_in[6 * L + 0];
        ta.xp[i] = (const float*)d_in[6 * L + 1];
        ta.h[i]  = (const float*)d_in[6 * L + 2];
        ta.c[i]  = (const float*)d_in[6 * L + 3];
        ta.w[i]  = (const float*)d_in[6 * L + 4];
        ta.bi[i] = (const float*)d_in[6 * L + 5];
        int S = NB * PP * HH[L] * HH[L];
        ta.oh[i] = out + obase[L];
        ta.oc[i] = out + obase[L] + S;
    }
    tiny_pre_kernel<<<dim3(31, NB, 6), 256, 0, stream>>>(ta, inT, maxslots);
    pack_tiny_kernel<<<dim3(256, 1, 3), 256, 0, stream>>>(ta, apT0, apT1, apT2, maxslots);
    conv_tiny_kernel<<<dim3(4, NB, 3), 512, 0, stream>>>(ta, inT, apT0, apT1, apT2);
}

// Round 13
// 380.887 us; speedup vs baseline: 1.5114x; 1.5114x over previous
//
#include <hip/hip_runtime.h>
#include <hip/hip_bf16.h>
#include <cstdint>
#include <cstddef>

#define PD 11
#define PP 121
#define NB 8

typedef _Float16 f16x8 __attribute__((ext_vector_type(8)));
typedef float    f32x4 __attribute__((ext_vector_type(4)));

#define GLOAD16(SRC, DST) __builtin_amdgcn_global_load_lds( \
    (const __attribute__((address_space(1))) void*)(SRC),   \
    (__attribute__((address_space(3))) void*)(DST), 16, 0, 0)

struct TinyArgs {
    const float* x[3]; const float* xp[3]; const float* h[3];
    const float* c[3]; const float* w[3]; const float* bi[3];
    float* oh[3]; float* oc[3];
};

// ---------------------------------------------------------------------------
__global__ void init_kernel(unsigned* __restrict__ slots, float* __restrict__ zg) {
    int t = threadIdx.x;
    if (t < 8) slots[t] = 0x007FFFFFu;  // enc(-inf)
    for (int i = t; i < 1024; i += 256) zg[i] = 0.f;
}

__device__ __forceinline__ float decode_max(const unsigned* slot) {
    unsigned mu = *slot;
    return (mu & 0x80000000u) ? __uint_as_float(mu ^ 0x80000000u) : __uint_as_float(~mu);
}

// ---------------------------------------------------------------------------
// fused fp32 NCHW -> fp16 NHWC transpose for x AND xp (blockIdx.z selects).
template<int C, int H, int TPX>
__global__ __launch_bounds__(256) void tpose_kernel(
    const float* __restrict__ xin, const float* __restrict__ xpin,
    _Float16* __restrict__ xT, _Float16* __restrict__ xpT)
{
    constexpr int W = H;
    const float* in  = blockIdx.z ? xpin : xin;
    _Float16*   out  = blockIdx.z ? xpT  : xT;
    const int by = blockIdx.y;
    const int b  = by / H, y = by % H;
    constexpr int NXT = W / TPX;
    const int x0 = (blockIdx.x % NXT) * TPX;
    const int cc = (blockIdx.x / NXT) * 64;
    __shared__ float s[64][36];

    constexpr int NF4 = 64 * TPX / 4;
    for (int f = threadIdx.x; f < NF4; f += 256) {
        int r  = f / (TPX / 4);
        int xq = f % (TPX / 4);
        int col = (xq * 4) ^ (((r >> 3) & 7) * 4);
        *(float4*)&s[r][col] =
            *(const float4*)&in[((size_t)(b * C + cc + r) * H + y) * W + x0 + xq * 4];
    }
    __syncthreads();
    constexpr int NWT = TPX * 8;
    for (int t = threadIdx.x; t < NWT; t += 256) {
        int pix = t >> 3, ck = t & 7;
        union { _Float16 h[8]; f16x8 v; } d;
#pragma unroll
        for (int j = 0; j < 8; ++j)
            d.h[j] = (_Float16)s[ck * 8 + j][pix ^ (ck * 4)];
        *(f16x8*)&out[((size_t)(b * H + y) * W + x0 + pix) * C + cc + ck * 8] = d.v;
    }
}

// ---------------------------------------------------------------------------
// MFMA correlation, double-buffered gload_lds staging. RAW leaky'd corr ->
// inT channels [0,128) + block max -> atomicMax.
template<int C, int H, int TSY, int TSX>
__global__ __launch_bounds__(512, 2) void corr_mfma_kernel(
    const _Float16* __restrict__ xT, const _Float16* __restrict__ xpT,
    const _Float16* __restrict__ zg,
    _Float16* __restrict__ inT, unsigned* __restrict__ slot)
{
    constexpr int W  = H;
    constexpr int HY = TSY + 10, HX = TSX + 10;
    constexpr int MZ = HY * HX;
    constexpr int MT = (MZ + 15) / 16;
    constexpr int MTP = MT * 16;
    constexpr int MFRAG = (MT + 7) / 8;
    constexpr int NPX = TSY * TSX;
    constexpr int NT  = NPX / 16;
    constexpr int KC  = C / 32;
    constexpr int ABYTES = MTP * 64;
    constexpr int BUF    = ABYTES + NPX * 64;
    constexpr int NLOAD  = BUF / 1024;
    constexpr int ST2    = NPX + 8;
    constexpr int ST_B   = MTP * ST2 * 2;
    constexpr int LDS_B  = (2 * BUF > ST_B) ? 2 * BUF : ST_B;
    __shared__ char smem[LDS_B];
    __shared__ float sred[8];

    const int tid  = threadIdx.x;
    const int b    = blockIdx.y;
    constexpr int TXT = W / TSX;
    const int y0 = (blockIdx.x / TXT) * TSY;
    const int x0 = (blockIdx.x % TXT) * TSX;
    const int w = tid >> 6, lane = tid & 63;
    const int lcol = lane & 15, lkg = lane >> 4;

    auto STAGE = [&](int bufsel, int kc) {
        char* dstb = smem + bufsel * BUF;
        int c = lane & 3;
        for (int it = w; it < NLOAD; it += 8) {
            const void* src;
            if (it < MTP / 16) {
                int z = it * 16 + (lane >> 2);
                int zy = y0 + z / HX - 5, zx = x0 + z % HX - 5;
                if (z < MZ && zy >= 0 && zy < H && zx >= 0 && zx < W)
                    src = xpT + ((size_t)(b * H + zy) * W + zx) * C + kc * 32 + ((c ^ (z >> 2)) & 3) * 8;
                else
                    src = zg + lane * 8;
            } else {
                int p = (it - MTP / 16) * 16 + (lane >> 2);
                int gy = y0 + p / TSX, gx = x0 + p % TSX;
                src = xT + ((size_t)(b * H + gy) * W + gx) * C + kc * 32 + ((c ^ (p >> 2)) & 3) * 8;
            }
            GLOAD16(src, dstb + it * 1024);
        }
    };

    f32x4 acc[MFRAG][NT];
#pragma unroll
    for (int i = 0; i < MFRAG; ++i)
#pragma unroll
        for (int nt = 0; nt < NT; ++nt)
            acc[i][nt] = (f32x4){0.f, 0.f, 0.f, 0.f};

    STAGE(0, 0);
    __syncthreads();
#pragma unroll 1
    for (int kc = 0; kc < KC; ++kc) {
        if (kc + 1 < KC) STAGE((kc + 1) & 1, kc + 1);
        const char* bb = smem + (kc & 1) * BUF;
        f16x8 bF[NT];
#pragma unroll
        for (int nt = 0; nt < NT; ++nt) {
            int p = nt * 16 + lcol;
            bF[nt] = *(const f16x8*)(bb + ABYTES + p * 64 + (((lkg ^ (p >> 2)) & 3) << 4));
        }
#pragma unroll
        for (int i = 0; i < MFRAG; ++i) {
            int mt = w + i * 8;
            if (mt < MT) {
                int z = mt * 16 + lcol;
                f16x8 aF = *(const f16x8*)(bb + z * 64 + (((lkg ^ (z >> 2)) & 3) << 4));
#pragma unroll
                for (int nt = 0; nt < NT; ++nt)
                    acc[i][nt] = __builtin_amdgcn_mfma_f32_16x16x32_f16(aF, bF[nt], acc[i][nt], 0, 0, 0);
            }
        }
        __syncthreads();
    }

    _Float16* sT = (_Float16*)smem;
#pragma unroll
    for (int i = 0; i < MFRAG; ++i) {
        int mt = w + i * 8;
        if (mt >= MT) continue;
        int z0 = mt * 16 + lkg * 4;
#pragma unroll
        for (int nt = 0; nt < NT; ++nt) {
            int p = nt * 16 + lcol;
#pragma unroll
            for (int r = 0; r < 4; ++r)
                sT[(z0 + r) * ST2 + p] = (_Float16)acc[i][nt][r];
        }
    }
    __syncthreads();

    float lmax = -3.4e38f;
    if (tid < NPX * 8) {
        int p  = tid >> 3;
        int qg = tid & 7;
        int py = p / TSX, px = p % TSX;
        size_t pix = (size_t)(b * H + y0 + py) * W + (x0 + px);
        unsigned* dst = (unsigned*)(inT + pix * 256) + qg * 8;
#pragma unroll
        for (int j2 = 0; j2 < 8; ++j2) {
            int q0 = qg * 16 + j2 * 2, q1 = q0 + 1;
            int qc0 = q0 < PP ? q0 : PP - 1;
            int qc1 = q1 < PP ? q1 : PP - 1;
            float v0 = (float)sT[((py + qc0 / PD) * HX + (px + qc0 % PD)) * ST2 + p];
            float v1 = (float)sT[((py + qc1 / PD) * HX + (px + qc1 % PD)) * ST2 + p];
            v0 = v0 > 0.f ? v0 : 0.01f * v0;
            v1 = v1 > 0.f ? v1 : 0.01f * v1;
            if (q0 < PP) lmax = fmaxf(lmax, v0);
            if (q1 < PP) lmax = fmaxf(lmax, v1);
            union { _Float16 h[2]; unsigned u; } pk;
            pk.h[0] = (_Float16)v0; pk.h[1] = (_Float16)v1;
            dst[j2] = pk.u;
        }
    }
    for (int off = 32; off; off >>= 1) lmax = fmaxf(lmax, __shfl_down(lmax, off));
    if (lane == 0) sred[w] = lmax;
    __syncthreads();
    if (tid == 0) {
        float m = sred[0];
        for (int i = 1; i < 8; ++i) m = fmaxf(m, sred[i]);
        unsigned eb = __float_as_uint(m);
        eb = (eb & 0x80000000u) ? ~eb : (eb | 0x80000000u);
        atomicMax(slot, eb);
    }
}

// ---------------------------------------------------------------------------
// coalesced weight pack body (LDS-staged, u32 fragment writes, prescale).
__device__ __forceinline__ void pack2_body(
    const float* __restrict__ Wsrc, _Float16* __restrict__ Apack,
    float inv, int mt, int ks, int tid, float* __restrict__ sW)
{
    const int icmax9 = (242 - ks * 32) * 9;
    for (int f = tid; f < 16 * 288; f += 256) {
        int r = f / 288, i = f - r * 288;
        int m = mt * 16 + r;
        float v = 0.f;
        if (m < 484 && i < icmax9) {
            int q = m >> 2, g = m & 3;
            v = Wsrc[((size_t)(g * PP + q) * 242 + ks * 32) * 9 + i];
        }
        sW[r * 292 + i] = v;
    }
    __syncthreads();
    const int o = tid * 2;
    const int l = o >> 3, e0 = o & 7;
    const int r = l & 15;
    const int klbase = (l >> 4) * 8;
    const int ic0 = ks * 32 + klbase + e0;
#pragma unroll 1
    for (int k9 = 0; k9 < 9; ++k9) {
        float v0 = sW[r * 292 + (klbase + e0) * 9 + k9];
        float v1 = sW[r * 292 + (klbase + e0 + 1) * 9 + k9];
        if (ic0 < PP)     v0 *= inv;
        if (ic0 + 1 < PP) v1 *= inv;
        union { _Float16 h[2]; unsigned u; } pk;
        pk.h[0] = (_Float16)v0; pk.h[1] = (_Float16)v1;
        *(unsigned*)((char*)Apack + (size_t)((k9 * 8 + ks) * 32 + mt) * 1024 + o * 2) = pk.u;
    }
}

// ---------------------------------------------------------------------------
// merged post-corr kernel for big levels: blocks [0,256) = pack, rest = h-fill.
// (No race: corr for this level completed in the PREVIOUS launch.)
template<int H>
__global__ __launch_bounds__(256) void post_kernel(
    _Float16* __restrict__ inT, const float* __restrict__ hpre,
    const float* __restrict__ Wsrc, _Float16* __restrict__ Apack,
    const unsigned* __restrict__ slot)
{
    __shared__ float sW[16 * 292];
    const int bx = blockIdx.x, tid = threadIdx.x;
    if (bx < 256) {
        float inv = 1.0f / decode_max(slot);
        pack2_body(Wsrc, Apack, inv, bx >> 3, bx & 7, tid, sW);
        return;
    }
    constexpr int HW = H * H;
    constexpr int NP = NB * HW;
    int idx = (bx - 256) * 256 + tid;
    if (idx >= NP * 17) return;
    int c = 15 + idx / NP;
    int pix = idx % NP;
    int b = pix / HW, p2 = pix % HW;
    _Float16* base = inT + (size_t)pix * 256 + c * 8;
    union { _Float16 h[8]; uint4 u; } d;
    if (c == 15) {
        d.u = *(const uint4*)base;
#pragma unroll
        for (int j = 1; j < 8; ++j)
            d.h[j] = (_Float16)hpre[((size_t)b * PP + (j - 1)) * HW + p2];
    } else if (c <= 29) {
#pragma unroll
        for (int j = 0; j < 8; ++j)
            d.h[j] = (_Float16)hpre[((size_t)b * PP + (c * 8 + j - 121)) * HW + p2];
    } else if (c == 30) {
        d.h[0] = (_Float16)hpre[((size_t)b * PP + 119) * HW + p2];
        d.h[1] = (_Float16)hpre[((size_t)b * PP + 120) * HW + p2];
#pragma unroll
        for (int j = 2; j < 8; ++j) d.h[j] = (_Float16)0.f;
    } else {
#pragma unroll
        for (int j = 0; j < 8; ++j) d.h[j] = (_Float16)0.f;
    }
    *(uint4*)base = d.u;
}

// ---------------------------------------------------------------------------
// tiny levels (H=8/4/2): corr and h-fill in SEPARATE launches (r12 race fix).
template<int H>
__device__ void corr_small_body(const float* __restrict__ x, const float* __restrict__ xp,
    _Float16* __restrict__ inT, unsigned* __restrict__ slot, int b)
{
    constexpr int PX  = H * H;
    constexpr int TOT = PX * PP;
    const int o = blockIdx.x * 256 + threadIdx.x;
    float v = -3.4e38f;
    if (o < TOT) {
        int p = o / PP;
        int q = o - p * PP;
        int y = p / H, xx = p % H;
        int sy = y + q / PD - 5, sx = xx + q % PD - 5;
        float acc = 0.f;
        if (sy >= 0 && sy < H && sx >= 0 && sx < H) {
            const float* xb  = x  + (size_t)b * 256 * PX + p;
            const float* xpb = xp + (size_t)b * 256 * PX + sy * H + sx;
#pragma unroll 8
            for (int c = 0; c < 256; ++c)
                acc = fmaf(xb[c * PX], xpb[c * PX], acc);
        }
        float lv = acc > 0.f ? acc : 0.01f * acc;
        inT[((size_t)b * PX + p) * 256 + q] = (_Float16)lv;
        v = lv;
    }
    for (int off = 32; off; off >>= 1) v = fmaxf(v, __shfl_down(v, off));
    __shared__ float sred[4];
    if ((threadIdx.x & 63) == 0) sred[threadIdx.x >> 6] = v;
    __syncthreads();
    if (threadIdx.x == 0) {
        float m = fmaxf(fmaxf(sred[0], sred[1]), fmaxf(sred[2], sred[3]));
        unsigned eb = __float_as_uint(m);
        eb = (eb & 0x80000000u) ? ~eb : (eb | 0x80000000u);
        atomicMax(slot, eb);
    }
}

template<int H>
__device__ void hfill_body(_Float16* __restrict__ inT, const float* __restrict__ hpre, int b)
{
    constexpr int HW = H * H;
    int idx = blockIdx.x * 256 + threadIdx.x;
    if (idx >= HW * 17) return;
    int c = 15 + idx / HW;
    int p2 = idx % HW;
    _Float16* base = inT + ((size_t)b * HW + p2) * 256 + c * 8;
    union { _Float16 h[8]; uint4 u; } d;
    if (c == 15) {
        d.u = *(const uint4*)base;
#pragma unroll
        for (int j = 1; j < 8; ++j)
            d.h[j] = (_Float16)hpre[((size_t)b * PP + (j - 1)) * HW + p2];
    } else if (c <= 29) {
#pragma unroll
        for (int j = 0; j < 8; ++j)
            d.h[j] = (_Float16)hpre[((size_t)b * PP + (c * 8 + j - 121)) * HW + p2];
    } else if (c == 30) {
        d.h[0] = (_Float16)hpre[((size_t)b * PP + 119) * HW + p2];
        d.h[1] = (_Float16)hpre[((size_t)b * PP + 120) * HW + p2];
#pragma unroll
        for (int j = 2; j < 8; ++j) d.h[j] = (_Float16)0.f;
    } else {
#pragma unroll
        for (int j = 0; j < 8; ++j) d.h[j] = (_Float16)0.f;
    }
    *(uint4*)base = d.u;
}

__global__ __launch_bounds__(256) void tiny_corr_kernel(
    TinyArgs ta, _Float16* __restrict__ inT, unsigned* __restrict__ slots)
{
    const int z = blockIdx.z, b = blockIdx.y;
    if      (z == 0) corr_small_body<8>(ta.x[0], ta.xp[0], inT,          slots + 3, b);
    else if (z == 1) corr_small_body<4>(ta.x[1], ta.xp[1], inT + 131072, slots + 4, b);
    else             corr_small_body<2>(ta.x[2], ta.xp[2], inT + 163840, slots + 5, b);
}

__global__ __launch_bounds__(256) void tiny_hfill_kernel(
    TinyArgs ta, _Float16* __restrict__ inT)
{
    const int z = blockIdx.z, b = blockIdx.y;
    if      (z == 0) hfill_body<8>(inT,          ta.h[0], b);
    else if (z == 1) hfill_body<4>(inT + 131072, ta.h[1], b);
    else             hfill_body<2>(inT + 163840, ta.h[2], b);
}

__global__ __launch_bounds__(256) void pack_tiny_kernel(
    TinyArgs ta, _Float16* __restrict__ a0, _Float16* __restrict__ a1,
    _Float16* __restrict__ a2, const unsigned* __restrict__ slots)
{
    __shared__ float sW[16 * 292];
    const int z = blockIdx.z;
    _Float16* Ap = (z == 0) ? a0 : (z == 1 ? a1 : a2);
    float inv = 1.0f / decode_max(slots + 3 + z);
    pack2_body(ta.w[z], Ap, inv, blockIdx.x >> 3, blockIdx.x & 7, threadIdx.x, sW);
}

// ---------------------------------------------------------------------------
// conv v3 (ROUND-10 VERIFIED STRUCTURE): TR x 16 tile, gload_lds staging,
// A-fragment register double-buffer ONLY (no B-dbuf, no setprio — r12's
// additions caused scratch spill). VGPR ~60, 91 us @ L0.
template<int H, int TR, int MSPLIT>
__global__ __launch_bounds__(512, 4) void conv_mfma3_kernel(
    const _Float16* __restrict__ inT, const float* __restrict__ cpre,
    const _Float16* __restrict__ Apack, const float* __restrict__ bias,
    const _Float16* __restrict__ zg,
    float* __restrict__ outh, float* __restrict__ outc)
{
    constexpr int W = H;
    constexpr int TC = 16, SR = TC + 2;
    constexpr int NPOS = (TR + 2) * SR;
    constexpr int MT_BLK = 32 / MSPLIT;
    constexpr int AF = 4 / MSPLIT;
    constexpr int TILES_X = W / TC;
    __shared__ _Float16 sIn[NPOS * 256];

    const int tid  = threadIdx.x;
    const int b    = blockIdx.y;
    const int mblk = blockIdx.z;
    const int tile = blockIdx.x;
    const int ty0  = (tile / TILES_X) * TR;
    const int tx0  = (tile % TILES_X) * TC;
    const int w = tid >> 6, lane = tid & 63;
    const int lcol = lane & 15, kg = lane >> 4;

    char* sB = (char*)sIn;
    for (int it = w; it < NPOS / 2; it += 8) {
        int r  = it * 2 + (lane >> 5);
        int c  = lane & 31;
        int iy = r / SR, ix = r % SR;
        int gy = ty0 + iy - 1, gx = tx0 + ix - 1;
        const void* src;
        if (gy >= 0 && gy < H && gx >= 0 && gx < W)
            src = inT + ((size_t)(b * H + gy) * W + gx) * 256 + (c ^ (ix & 7)) * 8;
        else
            src = zg + lane * 8;
        GLOAD16(src, sB + it * 1024);
    }
    __syncthreads();

    const int mtg0 = mblk * MT_BLK + w * AF;

    f32x4 acc[AF * TR];
#pragma unroll
    for (int a = 0; a < AF; ++a) {
        int q = (mtg0 + a) * 4 + kg;
        f32x4 bv;
#pragma unroll
        for (int r = 0; r < 4; ++r) bv[r] = (q < PP) ? bias[r * PP + q] : 0.f;
#pragma unroll
        for (int j = 0; j < TR; ++j) acc[a * TR + j] = bv;
    }

    const f16x8* apL = (const f16x8*)Apack + (size_t)mtg0 * 64 + lane;

    auto COMPUTE = [&](const f16x8* af, int s) {
        int k9 = s >> 3, ks = s & 7;
        int ky = k9 / 3, kx = k9 - ky * 3;
        int ix = lcol + kx;
        int xsw = (ix & 7) << 4;
        int cb  = kg * 16 + ks * 64;
#pragma unroll
        for (int j = 0; j < TR; ++j) {
            int addr = ((((j + ky) * SR + ix) * 512) + cb) ^ xsw;
            f16x8 bf = *(const f16x8*)(sB + addr);
#pragma unroll
            for (int a = 0; a < AF; ++a)
                acc[a * TR + j] = __builtin_amdgcn_mfma_f32_16x16x32_f16(af[a], bf, acc[a * TR + j], 0, 0, 0);
        }
    };

    f16x8 afA[AF], afB[AF];
#pragma unroll
    for (int a = 0; a < AF; ++a) afA[a] = apL[a * 64];
#pragma unroll 1
    for (int s2 = 0; s2 < 36; ++s2) {
        const f16x8* apB = apL + (size_t)(s2 * 2 + 1) * 2048;
#pragma unroll
        for (int a = 0; a < AF; ++a) afB[a] = apB[a * 64];
        COMPUTE(afA, s2 * 2);
        if (s2 < 35) {
            const f16x8* apA = apL + (size_t)(s2 * 2 + 2) * 2048;
#pragma unroll
            for (int a = 0; a < AF; ++a) afA[a] = apA[a * 64];
        }
        COMPUTE(afB, s2 * 2 + 1);
    }

#pragma unroll
    for (int a = 0; a < AF; ++a) {
        int q = (mtg0 + a) * 4 + kg;
        if (q >= PP) continue;
#pragma unroll
        for (int j = 0; j < TR; ++j) {
            int y = ty0 + j, x = tx0 + lcol;
            if (y >= H) continue;
            float ai = acc[a * TR + j][0];
            float af_ = acc[a * TR + j][1];
            float ao = acc[a * TR + j][2];
            float ag = acc[a * TR + j][3];
            float ig = 1.f / (1.f + expf(-ai));
            float fg = 1.f / (1.f + expf(-af_));
            float og = 1.f / (1.f + expf(-ao));
            float gg = tanhf(ag);
            size_t oidx = (((size_t)b * PP + q) * H + y) * W + x;
            float cp = cpre[oidx];
            float cn = fg * cp + ig * gg;
            outh[oidx] = og * tanhf(cn);
            outc[oidx] = cn;
        }
    }
}

// ---------------------------------------------------------------------------
// batched tiny conv: whole image per block, M-split over blockIdx.x, level
// over blockIdx.z.
template<int H>
__device__ void conv_tiny_body(const _Float16* __restrict__ inT,
    const float* __restrict__ cpre, const _Float16* __restrict__ Apack,
    const float* __restrict__ bias, float* __restrict__ outh,
    float* __restrict__ outc, int b, int mblk, char* __restrict__ sB)
{
    constexpr int NPX = H * H;
    constexpr int NT  = (NPX + 15) / 16;
    constexpr int SR  = H + 2;
    constexpr int NPOS = SR * SR;
    const int tid = threadIdx.x;

    constexpr int CHUNKS = NPOS * 32;
    for (int flat = tid; flat < CHUNKS; flat += 512) {
        int cg  = flat & 31;
        int pos = flat >> 5;
        int iy = pos / SR, ix = pos % SR;
        int gy = iy - 1, gx = ix - 1;
        f16x8 v = {0, 0, 0, 0, 0, 0, 0, 0};
        if (gy >= 0 && gy < H && gx >= 0 && gx < H)
            v = *(const f16x8*)(inT + ((size_t)(b * H + gy) * H + gx) * 256 + cg * 8);
        int dst = (pos * 512 + cg * 16) ^ ((ix & 7) << 4);
        *(f16x8*)(sB + dst) = v;
    }
    __syncthreads();

    const int w = tid >> 6, lane = tid & 63;
    const int lcol = lane & 15, kg = lane >> 4;
    const int mt = mblk * 8 + w;
    const int q  = mt * 4 + kg;

    f32x4 acc[NT];
    f32x4 bv;
#pragma unroll
    for (int r = 0; r < 4; ++r) bv[r] = (q < PP) ? bias[r * PP + q] : 0.f;
#pragma unroll
    for (int nt = 0; nt < NT; ++nt) acc[nt] = bv;

#pragma unroll 1
    for (int k9 = 0; k9 < 9; ++k9) {
        const int ky = k9 / 3, kx = k9 % 3;
        int basev[NT], xswv[NT];
#pragma unroll
        for (int nt = 0; nt < NT; ++nt) {
            int p = nt * 16 + lcol;
            int pc = (NPX < 16 && p >= NPX) ? 0 : p;
            int py = pc / H, px = pc % H;
            int iy = py + ky, ix = px + kx;
            basev[nt] = (iy * SR + ix) * 512 + kg * 16;
            xswv[nt]  = (ix & 7) << 4;
        }
        const f16x8* apb = (const f16x8*)Apack + ((size_t)(k9 * 8) * 32 + mt) * 64 + lane;
#pragma unroll 1
        for (int ks = 0; ks < 8; ++ks) {
            f16x8 bf[NT];
#pragma unroll
            for (int nt = 0; nt < NT; ++nt) {
                bf[nt] = *(const f16x8*)(sB + ((basev[nt] + ks * 64) ^ xswv[nt]));
                if (NPX < 16 && nt * 16 + lcol >= NPX) bf[nt] = (f16x8){};
            }
            f16x8 af = apb[(size_t)ks * 32 * 64];
#pragma unroll
            for (int nt = 0; nt < NT; ++nt)
                acc[nt] = __builtin_amdgcn_mfma_f32_16x16x32_f16(af, bf[nt], acc[nt], 0, 0, 0);
        }
    }

    if (q < PP) {
#pragma unroll
        for (int nt = 0; nt < NT; ++nt) {
            int p = nt * 16 + lcol;
            if (NPX < 16 && p >= NPX) continue;
            int py = p / H, px = p % H;
            float ai = acc[nt][0];
            float af_ = acc[nt][1];
            float ao = acc[nt][2];
            float ag = acc[nt][3];
            float ig = 1.f / (1.f + expf(-ai));
            float fg = 1.f / (1.f + expf(-af_));
            float og = 1.f / (1.f + expf(-ao));
            float gg = tanhf(ag);
            size_t oidx = (((size_t)b * PP + q) * H + py) * H + px;
            float cp = cpre[oidx];
            float cn = fg * cp + ig * gg;
            outh[oidx] = og * tanhf(cn);
            outc[oidx] = cn;
        }
    }
}

__global__ __launch_bounds__(512, 4) void conv_tiny_kernel(
    TinyArgs ta, const _Float16* __restrict__ inT,
    const _Float16* __restrict__ a0, const _Float16* __restrict__ a1,
    const _Float16* __restrict__ a2)
{
    __shared__ char sB[100 * 512];
    const int z = blockIdx.z, b = blockIdx.y, mblk = blockIdx.x;
    if      (z == 0) conv_tiny_body<8>(inT,          ta.c[0], a0, ta.bi[0], ta.oh[0], ta.oc[0], b, mblk, sB);
    else if (z == 1) conv_tiny_body<4>(inT + 131072, ta.c[1], a1, ta.bi[1], ta.oh[1], ta.oc[1], b, mblk, sB);
    else             conv_tiny_body<2>(inT + 163840, ta.c[2], a2, ta.bi[2], ta.oh[2], ta.oc[2], b, mblk, sB);
}

// ---------------------------------------------------------------------------
extern "C" void kernel_launch(void* const* d_in, const int* in_sizes, int n_in,
                              void* d_out, int out_size, void* d_ws, size_t ws_size,
                              hipStream_t stream) {
    (void)in_sizes; (void)n_in; (void)out_size; (void)ws_size;
    static const int HH[6] = {64, 32, 16, 8, 4, 2};

    unsigned* maxslots = (unsigned*)d_ws;
    _Float16* Apack = (_Float16*)((char*)d_ws + 256);
    _Float16* inT   = (_Float16*)((char*)d_ws + 2359808);
    _Float16* xT    = (_Float16*)((char*)d_ws + 19137024);
    _Float16* xpT   = (_Float16*)((char*)d_ws + 52691456);
    _Float16* zg    = (_Float16*)((char*)d_ws + 86245888);
    // tiny-level Apacks reuse the (dead-after-corr-L2) xT region
    _Float16* apT0 = (_Float16*)((char*)d_ws + 19137024);
    _Float16* apT1 = (_Float16*)((char*)d_ws + 19137024 + 2359296);
    _Float16* apT2 = (_Float16*)((char*)d_ws + 19137024 + 2 * 2359296);

    float* out = (float*)d_out;
    size_t obase[6];
    {
        size_t ob = 0;
        for (int L = 0; L < 6; ++L) { obase[L] = ob; ob += 2ull * NB * PP * HH[L] * HH[L]; }
    }

    init_kernel<<<1, 256, 0, stream>>>(maxslots, (float*)zg);

    // ---- big levels 0..2 ----
    for (int L = 0; L < 3; ++L) {
        const float* x    = (const float*)d_in[6 * L + 0];
        const float* xp   = (const float*)d_in[6 * L + 1];
        const float* h    = (const float*)d_in[6 * L + 2];
        const float* c    = (const float*)d_in[6 * L + 3];
        const float* Wsrc = (const float*)d_in[6 * L + 4];
        const float* bias = (const float*)d_in[6 * L + 5];
        int Hh = HH[L];
        int S = NB * PP * Hh * Hh;
        float* oh = out + obase[L];
        float* oc = out + obase[L] + S;

        switch (L) {
            case 0:
                tpose_kernel<512, 64, 32><<<dim3(16, NB * 64, 2), 256, 0, stream>>>(x, xp, xT, xpT);
                corr_mfma_kernel<512, 64, 8, 8><<<dim3(64, NB), 512, 0, stream>>>(xT, xpT, zg, inT, maxslots + 0);
                post_kernel<64><<<256 + (NB * 64 * 64 * 17 + 255) / 256, 256, 0, stream>>>(inT, h, Wsrc, Apack, maxslots + 0);
                conv_mfma3_kernel<64, 4, 1><<<dim3(64, 8, 1), 512, 0, stream>>>(inT, c, Apack, bias, zg, oh, oc);
                break;
            case 1:
                tpose_kernel<1024, 32, 32><<<dim3(16, NB * 32, 2), 256, 0, stream>>>(x, xp, xT, xpT);
                corr_mfma_kernel<1024, 32, 4, 8><<<dim3(32, NB), 512, 0, stream>>>(xT, xpT, zg, inT, maxslots + 1);
                post_kernel<32><<<256 + (NB * 32 * 32 * 17 + 255) / 256, 256, 0, stream>>>(inT, h, Wsrc, Apack, maxslots + 1);
                conv_mfma3_kernel<32, 4, 2><<<dim3(16, 8, 2), 512, 0, stream>>>(inT, c, Apack, bias, zg, oh, oc);
                break;
            case 2:
                tpose_kernel<512, 16, 16><<<dim3(8, NB * 16, 2), 256, 0, stream>>>(x, xp, xT, xpT);
                corr_mfma_kernel<512, 16, 4, 4><<<dim3(16, NB), 512, 0, stream>>>(xT, xpT, zg, inT, maxslots + 2);
                post_kernel<16><<<256 + (NB * 16 * 16 * 17 + 255) / 256, 256, 0, stream>>>(inT, h, Wsrc, Apack, maxslots + 2);
                conv_mfma3_kernel<16, 4, 4><<<dim3(4, 8, 4), 512, 0, stream>>>(inT, c, Apack, bias, zg, oh, oc);
                break;
        }
    }

    // ---- tiny levels 3..5, batched (corr and hfill SEPARATE launches) ----
    TinyArgs ta;
    for (int i = 0; i < 3; ++i) {
        int L = 3 + i;
        ta.x[i]  = (const float*)d_in[6 * L + 0];
        ta.xp[i] = (const float*)d_in[6 * L + 1];
        ta.h[i]  = (const float*)d_in[6 * L + 2];
        ta.c[i]  = (const float*)d_in[6 * L + 3];
        ta.w[i]  = (const float*)d_in[6 * L + 4];
        ta.bi[i] = (const float*)d_in[6 * L + 5];
        int S = NB * PP * HH[L] * HH[L];
        ta.oh[i] = out + obase[L];
        ta.oc[i] = out + obase[L] + S;
    }
    tiny_corr_kernel<<<dim3(31, NB, 3), 256, 0, stream>>>(ta, inT, maxslots);
    tiny_hfill_kernel<<<dim3(5, NB, 3), 256, 0, stream>>>(ta, inT);
    pack_tiny_kernel<<<dim3(256, 1, 3), 256, 0, stream>>>(ta, apT0, apT1, apT2, maxslots);
    conv_tiny_kernel<<<dim3(4, NB, 3), 512, 0, stream>>>(ta, inT, apT0, apT1, apT2);
}